// Round 3
// baseline (243.347 us; speedup 1.0000x reference)
//
#include <hip/hip_runtime.h>

// Problem constants (B=2, S=2048, D=1024, H=16, HD=64). fp32 in / fp32 out.
#define NB 2
#define NS 2048
#define ND 1024
#define NH 16
#define NHD 64
#define QLD (3 * ND)   // qkv workspace row stride in elements = 3072
#define KVB 128        // kv tile rows per phase (halves phase count vs 64)
#define PADP 136       // Ps row stride (u16); 272 B = 16B-aligned rows
#define PADV 136       // Vt row stride (u16); 272 B = 16B-aligned rows

typedef unsigned short u16;
typedef __attribute__((ext_vector_type(8))) short short8;   // 8 x bf16 (4 VGPRs)
typedef __attribute__((ext_vector_type(4))) float f32x4;

__device__ __forceinline__ u16 f2b(float f) {
    unsigned int x = __float_as_uint(f);
    return (u16)((x + 0x7fffu + ((x >> 16) & 1u)) >> 16);  // RNE
}

// v_cvt_pk_bf16_f32: low16 = bf16(lo), high16 = bf16(hi), RNE. Pure (non-volatile).
__device__ __forceinline__ unsigned int cvtpk(float lo, float hi) {
    unsigned int r;
    asm("v_cvt_pk_bf16_f32 %0, %1, %2" : "=v"(r) : "v"(lo), "v"(hi));
    return r;
}

// ---------------------------------------------------------------------------
// fp32 -> bf16 elementwise cast (for x). n must be a multiple of 8.
__global__ __launch_bounds__(256) void convert_bf16(
    const float* __restrict__ src, u16* __restrict__ dst, int n)
{
    const int i = (blockIdx.x * 256 + threadIdx.x) * 8;
    if (i >= n) return;
    float4 a = *(const float4*)(src + i);
    float4 b = *(const float4*)(src + i + 4);
    *(ushort4*)(dst + i)     = make_ushort4(f2b(a.x), f2b(a.y), f2b(a.z), f2b(a.w));
    *(ushort4*)(dst + i + 4) = make_ushort4(f2b(b.x), f2b(b.y), f2b(b.z), f2b(b.w));
}

// ---------------------------------------------------------------------------
// W[K,N] fp32 -> WT[N,K] bf16 (64x64 tiles via LDS).
__global__ __launch_bounds__(256) void transpose_bf16(
    const float* __restrict__ W, u16* __restrict__ WT, int K, int N)
{
    __shared__ u16 Ts[64 * 72];
    const int t = threadIdx.x;
    const int k0 = blockIdx.y << 6, n0 = blockIdx.x << 6;
    const int r = t >> 4, c = (t & 15) << 2;
    #pragma unroll
    for (int rr = 0; rr < 64; rr += 16) {
        float4 v = *(const float4*)&W[(size_t)(k0 + r + rr) * N + n0 + c];
        Ts[(c + 0) * 72 + r + rr] = f2b(v.x);
        Ts[(c + 1) * 72 + r + rr] = f2b(v.y);
        Ts[(c + 2) * 72 + r + rr] = f2b(v.z);
        Ts[(c + 3) * 72 + r + rr] = f2b(v.w);
    }
    __syncthreads();
    const int n = t >> 2, cc = (t & 3) << 4;
    uint4 a = *(const uint4*)&Ts[n * 72 + cc];
    uint4 b = *(const uint4*)&Ts[n * 72 + cc + 8];
    *(uint4*)&WT[(size_t)(n0 + n) * K + k0 + cc]     = a;
    *(uint4*)&WT[(size_t)(n0 + n) * K + k0 + cc + 8] = b;
}

// ---------------------------------------------------------------------------
// bf16 MFMA GEMM (m97 structure): C[M,N] = A[M,K] @ BT[N,K]^T + bias[N].
// 128xBN tile, 256 threads, BK=32, global_load_lds w=16, XOR swizzle.
template <int BN, bool STORE_BF16>
__global__ __launch_bounds__(256) void gemm_mfma(
    const u16* __restrict__ A, const u16* __restrict__ BT,
    const float* __restrict__ bias,
    void* __restrict__ C, int M, int N, int K)
{
    constexpr int BIS = BN / 64;   // B staging iterations (256 lanes x 16B each)
    constexpr int NJ  = BN / 32;   // per-wave N fragments (wave covers BN/2 cols)
    __shared__ u16 As[128 * 32];
    __shared__ u16 Bs[BN * 32];

    const int tid = threadIdx.x;
    const int wave = tid >> 6, lane = tid & 63;
    const int col = lane & 15, quad = lane >> 4;
    const int wm = wave >> 1, wn = wave & 1;
    const int row0 = blockIdx.y << 7, col0 = blockIdx.x * BN;

    f32x4 acc[4][NJ] = {};

    const u16* asrc[2];
    u16* adst[2];
    #pragma unroll
    for (int is = 0; is < 2; ++is) {
        const int J = is * 256 + wave * 64 + lane;
        const int m = J >> 2;
        const int q = (J & 3) ^ ((m >> 1) & 3);
        asrc[is] = A + (size_t)(row0 + m) * K + q * 8;
        adst[is] = &As[(size_t)(is * 256 + wave * 64) * 8];
    }
    const u16* bsrc[BIS];
    u16* bdst[BIS];
    #pragma unroll
    for (int is = 0; is < BIS; ++is) {
        const int J = is * 256 + wave * 64 + lane;
        const int m = J >> 2;
        const int q = (J & 3) ^ ((m >> 1) & 3);
        bsrc[is] = BT + (size_t)(col0 + m) * K + q * 8;
        bdst[is] = &Bs[(size_t)(is * 256 + wave * 64) * 8];
    }

    for (int kk = 0; kk < K; kk += 32) {
        __syncthreads();
        #pragma unroll
        for (int is = 0; is < 2; ++is)
            __builtin_amdgcn_global_load_lds(
                (const __attribute__((address_space(1))) unsigned int*)(asrc[is] + kk),
                (__attribute__((address_space(3))) unsigned int*)adst[is], 16, 0, 0);
        #pragma unroll
        for (int is = 0; is < BIS; ++is)
            __builtin_amdgcn_global_load_lds(
                (const __attribute__((address_space(1))) unsigned int*)(bsrc[is] + kk),
                (__attribute__((address_space(3))) unsigned int*)bdst[is], 16, 0, 0);
        __syncthreads();

        short8 af[4], bf[NJ];
        #pragma unroll
        for (int i = 0; i < 4; ++i) {
            const int m = wm * 64 + i * 16 + col;
            af[i] = *(const short8*)&As[(m * 4 + (quad ^ ((m >> 1) & 3))) * 8];
        }
        #pragma unroll
        for (int j = 0; j < NJ; ++j) {
            const int n = wn * (BN / 2) + j * 16 + col;
            bf[j] = *(const short8*)&Bs[(n * 4 + (quad ^ ((n >> 1) & 3))) * 8];
        }
        #pragma unroll
        for (int i = 0; i < 4; ++i)
            #pragma unroll
            for (int j = 0; j < NJ; ++j)
                acc[i][j] = __builtin_amdgcn_mfma_f32_16x16x32_bf16(
                    af[i], bf[j], acc[i][j], 0, 0, 0);
    }

    #pragma unroll
    for (int j = 0; j < NJ; ++j) {
        const int gc = col0 + wn * (BN / 2) + j * 16 + col;
        const float bj = bias[gc];
        #pragma unroll
        for (int i = 0; i < 4; ++i) {
            const int gr = row0 + wm * 64 + i * 16 + quad * 4;
            #pragma unroll
            for (int r = 0; r < 4; ++r) {
                const float v = acc[i][j][r] + bj;
                if (STORE_BF16)
                    ((u16*)C)[(size_t)(gr + r) * N + gc] = f2b(v);
                else
                    ((float*)C)[(size_t)(gr + r) * N + gc] = v;
            }
        }
    }
}

// ---------------------------------------------------------------------------
// MFMA flash attention: causal PAIRING (restored -- round-2 proved it is the
// load-balancing solution: unpaired triangular work has no refill and decays
// to the qt=31 tail) + KVB=128 kv-tiles.
// Round-1/2 evidence: duration is per-phase latency-chain x phase-count with
// only 2 blocks/CU of TLP; VALU cuts and ILP interleave were duration-neutral.
// => halve the phase count: KVB 64->128 halves barriers (66->34/block),
// Ps LDS round-trips and softmax shuffle pairs (33->17 processes/block,
// uniformly 16-17 with pairing), while total MFMA/exp work is unchanged.
// K-fragments are STREAMED from LDS inside qk (not cached: kb[8][2] would be
// +64 VGPR and risk the 256-VGPR 2-waves/SIMD cliff). Softmax in log2 domain
// (exp2f, scale folds log2e). Vt/Ps rows 16B-aligned -> single ds_read_b128.
__global__ __launch_bounds__(256) void attn_kernel(
    const u16* __restrict__ qkv, u16* __restrict__ vals)
{
    __shared__ u16 Ks[2][KVB * 64];   // 2 x 16 KB, XOR-swizzled 16B chunks
    __shared__ u16 Vt[64 * PADV];     // 17 KB, transposed V
    __shared__ u16 Ps[64 * PADP];     // 17 KB, per-wave 16-row strips

    const int tid = threadIdx.x;
    const int wave = tid >> 6, lane = tid & 63;
    const int col = lane & 15, quad = lane >> 4;
    const int qtA = blockIdx.x;          // 0..15
    const int qtB = 31 - qtA;            // 16..31
    const int bh = blockIdx.y;
    const int b = bh >> 4, h = bh & 15;
    const size_t base = (size_t)b * NS * QLD + (size_t)h * (3 * NHD);
    const int qloc = wave * 16 + col;    // this lane's query (tile-local)

    // DMA decomposition: J = is*256 + wave*64 + lane; row m=J>>3, stored
    // chunk position c'=J&7 holds source chunk c = c' ^ (m&7).
    int Jrow[4], Jcol[4];
    #pragma unroll
    for (int is = 0; is < 4; ++is) {
        const int J = is * 256 + wave * 64 + lane;
        Jrow[is] = J >> 3;
        Jcol[is] = ((J & 7) ^ (Jrow[is] & 7)) << 3;
    }

    auto stage_k = [&](int buf, int kt) {   // 128 rows, 4 DMA instrs
        #pragma unroll
        for (int is = 0; is < 4; ++is) {
            __builtin_amdgcn_global_load_lds(
                (const __attribute__((address_space(1))) unsigned int*)
                    (qkv + base + (size_t)(kt * KVB + Jrow[is]) * QLD + NHD + Jcol[is]),
                (__attribute__((address_space(3))) unsigned int*)
                    &Ks[buf][(size_t)(is * 256 + wave * 64) * 8], 16, 0, 0);
        }
    };
    auto stage_q = [&](int buf, int qt) {   // 64 rows into lower half
        #pragma unroll
        for (int is = 0; is < 2; ++is) {
            __builtin_amdgcn_global_load_lds(
                (const __attribute__((address_space(1))) unsigned int*)
                    (qkv + base + (size_t)(qt * 64 + Jrow[is]) * QLD + Jcol[is]),
                (__attribute__((address_space(3))) unsigned int*)
                    &Ks[buf][(size_t)(is * 256 + wave * 64) * 8], 16, 0, 0);
        }
    };
    // fragment read from swizzled Ks[buf]: row, d-half -> (row, half*32+quad*8..+7)
    auto read_frag = [&](int buf, int row, int half) -> short8 {
        const int blk = row * 8 + ((quad + (half << 2)) ^ (row & 7));
        return *(const short8*)&Ks[buf][blk << 3];
    };

    // V reg-staging lanes: vtx -> 4 d-values, vty -> 8 kv-rows
    const int vtx = tid & 15, vty = tid >> 4;
    const int vk0 = vty << 3, vd0 = vtx << 2;
    auto load_vregs = [&](int kt, ushort4* vr) {
        const u16* vsrc = qkv + base + (size_t)(kt * KVB + vk0) * QLD + 2 * NHD + vd0;
        #pragma unroll
        for (int j = 0; j < 8; ++j) vr[j] = *(const ushort4*)(vsrc + j * QLD);
    };
    auto write_vt = [&](const ushort4* vr) {
        *(ushort4*)&Vt[(vd0 + 0) * PADV + vk0]     = make_ushort4(vr[0].x, vr[1].x, vr[2].x, vr[3].x);
        *(ushort4*)&Vt[(vd0 + 0) * PADV + vk0 + 4] = make_ushort4(vr[4].x, vr[5].x, vr[6].x, vr[7].x);
        *(ushort4*)&Vt[(vd0 + 1) * PADV + vk0]     = make_ushort4(vr[0].y, vr[1].y, vr[2].y, vr[3].y);
        *(ushort4*)&Vt[(vd0 + 1) * PADV + vk0 + 4] = make_ushort4(vr[4].y, vr[5].y, vr[6].y, vr[7].y);
        *(ushort4*)&Vt[(vd0 + 2) * PADV + vk0]     = make_ushort4(vr[0].z, vr[1].z, vr[2].z, vr[3].z);
        *(ushort4*)&Vt[(vd0 + 2) * PADV + vk0 + 4] = make_ushort4(vr[4].z, vr[5].z, vr[6].z, vr[7].z);
        *(ushort4*)&Vt[(vd0 + 3) * PADV + vk0]     = make_ushort4(vr[0].w, vr[1].w, vr[2].w, vr[3].w);
        *(ushort4*)&Vt[(vd0 + 3) * PADV + vk0 + 4] = make_ushort4(vr[4].w, vr[5].w, vr[6].w, vr[7].w);
    };

    // ---- prologue: Q_A -> Ks[0], Q_B -> Ks[1] (lower halves); hoist frags --
    stage_q(0, qtA);
    stage_q(1, qtB);
    __syncthreads();
    short8 bqA0 = read_frag(0, qloc, 0), bqA1 = read_frag(0, qloc, 1);
    short8 bqB0 = read_frag(1, qloc, 0), bqB1 = read_frag(1, qloc, 1);
    __syncthreads();                     // Q reads done before K(0) overwrites

    f32x4 accA[4] = {}, accB[4] = {};
    float mA = -1e30f, lA = 0.f, mB = -1e30f, lB = 0.f;

    // S scaled by 1/8 * log2(e): softmax in log2 domain (exp2, no mul).
    const float SCL = 0.18033688f;       // 0.125 * 1.4426950408889634
    const float DTHR = 11.5416f;         // defer-max: 8 * log2(e)

    auto qk = [&](const short8& b0, const short8& b1, int buf, f32x4 (&s)[8]) {
        __builtin_amdgcn_s_setprio(1);
        #pragma unroll
        for (int kg = 0; kg < 8; ++kg) {
            short8 k0 = read_frag(buf, kg * 16 + col, 0);
            short8 k1 = read_frag(buf, kg * 16 + col, 1);
            s[kg] = __builtin_amdgcn_mfma_f32_16x16x32_bf16(k0, b0, s[kg], 0, 0, 0);
            s[kg] = __builtin_amdgcn_mfma_f32_16x16x32_bf16(k1, b1, s[kg], 0, 0, 0);
        }
        __builtin_amdgcn_s_setprio(0);
    };

    auto sm = [&](f32x4 (&s)[8], f32x4 (&acc)[4], float& m, float& l,
                  bool diag, int thresh) {
        #pragma unroll
        for (int kg = 0; kg < 8; ++kg)
            #pragma unroll
            for (int r = 0; r < 4; ++r) {
                float v = s[kg][r] * SCL;
                if (diag && (kg * 16 + quad * 4 + r > thresh)) v = -1e30f;
                s[kg][r] = v;
            }
        float mx = -1e30f;
        #pragma unroll
        for (int kg = 0; kg < 8; ++kg)
            mx = fmaxf(mx, fmaxf(fmaxf(s[kg][0], s[kg][1]), fmaxf(s[kg][2], s[kg][3])));
        mx = fmaxf(mx, __shfl_xor(mx, 16, 64));
        mx = fmaxf(mx, __shfl_xor(mx, 32, 64));
        // defer-max (T13): rescale only when max grew past m + 8 nats.
        if (!__all(mx <= m + DTHR)) {
            const float mn = fmaxf(m, mx);
            const float alpha = exp2f(m - mn);
            m = mn;
            l *= alpha;
            #pragma unroll
            for (int dg = 0; dg < 4; ++dg)
                #pragma unroll
                for (int r = 0; r < 4; ++r) acc[dg][r] *= alpha;
        }
        float psum = 0.f;
        #pragma unroll
        for (int kg = 0; kg < 8; ++kg) {
            float p0 = exp2f(s[kg][0] - m);
            float p1 = exp2f(s[kg][1] - m);
            float p2 = exp2f(s[kg][2] - m);
            float p3 = exp2f(s[kg][3] - m);
            psum += (p0 + p1) + (p2 + p3);
            uint2 w;
            w.x = cvtpk(p0, p1);
            w.y = cvtpk(p2, p3);
            *(uint2*)&Ps[qloc * PADP + kg * 16 + quad * 4] = w;
        }
        psum += __shfl_xor(psum, 16, 64);
        psum += __shfl_xor(psum, 32, 64);
        l += psum;
    };

    auto pv = [&](const short8 (&vb)[4][4], f32x4 (&acc)[4]) {
        short8 pb[4];
        #pragma unroll
        for (int c = 0; c < 4; ++c)
            pb[c] = *(const short8*)&Ps[qloc * PADP + c * 32 + quad * 8];
        __builtin_amdgcn_s_setprio(1);
        #pragma unroll
        for (int dg = 0; dg < 4; ++dg)
            #pragma unroll
            for (int c = 0; c < 4; ++c)
                acc[dg] = __builtin_amdgcn_mfma_f32_16x16x32_bf16(
                    vb[dg][c], pb[c], acc[dg], 0, 0, 0);
        __builtin_amdgcn_s_setprio(0);
    };

    // ---- software pipeline ----
    const int qtAh = qtA >> 1, qtBh = qtB >> 1;
    const int thA = qloc + ((qtA & 1) << 6);
    const int thB = qloc + ((qtB & 1) << 6);
    ushort4 vcur[8], vnxt[8];
    stage_k(0, 0);                       // K(0) -> Ks[0]
    load_vregs(0, vcur);

    for (int kt = 0; kt <= qtBh; ++kt) {
        const int cur = kt & 1, nxt = cur ^ 1;
        __syncthreads();                 // (A) drains K(kt) DMA + vcur loads
        write_vt(vcur);
        __syncthreads();                 // (B) Vt visible
        if (kt < qtBh) {
            stage_k(nxt, kt + 1);        // in flight during this compute phase
            load_vregs(kt + 1, vnxt);
        }

        // V fragments resident (64 VGPR); K fragments streamed inside qk.
        short8 vb[4][4];
        #pragma unroll
        for (int dg = 0; dg < 4; ++dg) {
            const int n = dg * 16 + col;
            #pragma unroll
            for (int c = 0; c < 4; ++c)
                vb[dg][c] = *(const short8*)&Vt[n * PADV + c * 32 + quad * 8];
        }

        {
            f32x4 s[8] = {};
            qk(bqB0, bqB1, cur, s);
            sm(s, accB, mB, lB, kt == qtBh, thB);
            pv(vb, accB);
        }
        if (kt <= qtAh) {
            f32x4 s[8] = {};
            qk(bqA0, bqA1, cur, s);
            sm(s, accA, mA, lA, kt == qtAh, thA);
            pv(vb, accA);
        }

        #pragma unroll
        for (int i = 0; i < 8; ++i) vcur[i] = vnxt[i];
    }

    // ---- epilogue: O^T rows d = dg*16 + quad*4 + r, query qloc ----
    {
        const float inv = 1.f / lA;
        const size_t rowoff = ((size_t)b * NS + qtA * 64 + qloc) * ND + h * NHD;
        #pragma unroll
        for (int dg = 0; dg < 4; ++dg) {
            uint2 o;
            o.x = cvtpk(accA[dg][0] * inv, accA[dg][1] * inv);
            o.y = cvtpk(accA[dg][2] * inv, accA[dg][3] * inv);
            *(uint2*)(vals + rowoff + dg * 16 + quad * 4) = o;
        }
    }
    {
        const float inv = 1.f / lB;
        const size_t rowoff = ((size_t)b * NS + qtB * 64 + qloc) * ND + h * NHD;
        #pragma unroll
        for (int dg = 0; dg < 4; ++dg) {
            uint2 o;
            o.x = cvtpk(accB[dg][0] * inv, accB[dg][1] * inv);
            o.y = cvtpk(accB[dg][2] * inv, accB[dg][3] * inv);
            *(uint2*)(vals + rowoff + dg * 16 + quad * 4) = o;
        }
    }
}

extern "C" void kernel_launch(void* const* d_in, const int* in_sizes, int n_in,
                              void* d_out, int out_size, void* d_ws, size_t ws_size,
                              hipStream_t stream)
{
    // inputs: x, mask(unused), W_qkv, b_qkv, W_o, b_o  -- all fp32
    const float* x    = (const float*)d_in[0];
    const float* Wqkv = (const float*)d_in[2];
    const float* bqkv = (const float*)d_in[3];
    const float* Wo   = (const float*)d_in[4];
    const float* bo   = (const float*)d_in[5];
    float* out = (float*)d_out;

    u16* x_bf   = (u16*)d_ws;                       //  4096*1024
    u16* WqkvT  = x_bf   + (size_t)4096 * 1024;     //  3072*1024  [N,K]
    u16* WoT    = WqkvT  + (size_t)3072 * 1024;     //  1024*1024  [N,K]
    u16* qkv    = WoT    + (size_t)1024 * 1024;     //  4096*3072
    u16* vals   = qkv    + (size_t)4096 * 3072;     //  4096*1024

    const int M = NB * NS;  // 4096

    convert_bf16<<<dim3(M * ND / (256 * 8)), dim3(256), 0, stream>>>(
        x, x_bf, M * ND);
    transpose_bf16<<<dim3(QLD / 64, ND / 64), dim3(256), 0, stream>>>(
        Wqkv, WqkvT, ND, QLD);
    transpose_bf16<<<dim3(ND / 64, ND / 64), dim3(256), 0, stream>>>(
        Wo, WoT, ND, ND);

    gemm_mfma<128, true><<<dim3(QLD / 128, M / 128), dim3(256), 0, stream>>>(
        x_bf, WqkvT, bqkv, qkv, M, QLD, ND);
    attn_kernel<<<dim3(16, NB * NH), dim3(256), 0, stream>>>(qkv, vals);
    gemm_mfma<64, false><<<dim3(ND / 64, M / 128), dim3(256), 0, stream>>>(
        vals, WoT, bo, out, M, ND, ND);
}

// Round 4
// 217.783 us; speedup vs baseline: 1.1174x; 1.1174x over previous
//
#include <hip/hip_runtime.h>

// Problem constants (B=2, S=2048, D=1024, H=16, HD=64). fp32 in / fp32 out.
#define NB 2
#define NS 2048
#define ND 1024
#define NH 16
#define NHD 64
#define QLD (3 * ND)   // qkv workspace row stride in elements = 3072
#define QTB 32         // query-tile rows (2-wave blocks)
#define KVB 64         // kv-tile rows per phase
#define PADP 72        // Ps row stride (u16); 144 B = 16B-aligned rows
#define PADV 68        // Vt row stride (u16)

typedef unsigned short u16;
typedef __attribute__((ext_vector_type(8))) short short8;   // 8 x bf16 (4 VGPRs)
typedef __attribute__((ext_vector_type(4))) short short4v;  // 4 x bf16 (2 VGPRs)
typedef __attribute__((ext_vector_type(4))) float f32x4;

__device__ __forceinline__ u16 f2b(float f) {
    unsigned int x = __float_as_uint(f);
    return (u16)((x + 0x7fffu + ((x >> 16) & 1u)) >> 16);  // RNE
}

// v_cvt_pk_bf16_f32: low16 = bf16(lo), high16 = bf16(hi), RNE. Pure (non-volatile).
__device__ __forceinline__ unsigned int cvtpk(float lo, float hi) {
    unsigned int r;
    asm("v_cvt_pk_bf16_f32 %0, %1, %2" : "=v"(r) : "v"(lo), "v"(hi));
    return r;
}

// ---------------------------------------------------------------------------
// fp32 -> bf16 elementwise cast (for x). n must be a multiple of 8.
__global__ __launch_bounds__(256) void convert_bf16(
    const float* __restrict__ src, u16* __restrict__ dst, int n)
{
    const int i = (blockIdx.x * 256 + threadIdx.x) * 8;
    if (i >= n) return;
    float4 a = *(const float4*)(src + i);
    float4 b = *(const float4*)(src + i + 4);
    *(ushort4*)(dst + i)     = make_ushort4(f2b(a.x), f2b(a.y), f2b(a.z), f2b(a.w));
    *(ushort4*)(dst + i + 4) = make_ushort4(f2b(b.x), f2b(b.y), f2b(b.z), f2b(b.w));
}

// ---------------------------------------------------------------------------
// W[K,N] fp32 -> WT[N,K] bf16 (64x64 tiles via LDS).
__global__ __launch_bounds__(256) void transpose_bf16(
    const float* __restrict__ W, u16* __restrict__ WT, int K, int N)
{
    __shared__ u16 Ts[64 * 72];
    const int t = threadIdx.x;
    const int k0 = blockIdx.y << 6, n0 = blockIdx.x << 6;
    const int r = t >> 4, c = (t & 15) << 2;
    #pragma unroll
    for (int rr = 0; rr < 64; rr += 16) {
        float4 v = *(const float4*)&W[(size_t)(k0 + r + rr) * N + n0 + c];
        Ts[(c + 0) * 72 + r + rr] = f2b(v.x);
        Ts[(c + 1) * 72 + r + rr] = f2b(v.y);
        Ts[(c + 2) * 72 + r + rr] = f2b(v.z);
        Ts[(c + 3) * 72 + r + rr] = f2b(v.w);
    }
    __syncthreads();
    const int n = t >> 2, cc = (t & 3) << 4;
    uint4 a = *(const uint4*)&Ts[n * 72 + cc];
    uint4 b = *(const uint4*)&Ts[n * 72 + cc + 8];
    *(uint4*)&WT[(size_t)(n0 + n) * K + k0 + cc]     = a;
    *(uint4*)&WT[(size_t)(n0 + n) * K + k0 + cc + 8] = b;
}

// ---------------------------------------------------------------------------
// bf16 MFMA GEMM (m97 structure): C[M,N] = A[M,K] @ BT[N,K]^T + bias[N].
// 128xBN tile, 256 threads, BK=32, global_load_lds w=16, XOR swizzle.
template <int BN, bool STORE_BF16>
__global__ __launch_bounds__(256) void gemm_mfma(
    const u16* __restrict__ A, const u16* __restrict__ BT,
    const float* __restrict__ bias,
    void* __restrict__ C, int M, int N, int K)
{
    constexpr int BIS = BN / 64;   // B staging iterations (256 lanes x 16B each)
    constexpr int NJ  = BN / 32;   // per-wave N fragments (wave covers BN/2 cols)
    __shared__ u16 As[128 * 32];
    __shared__ u16 Bs[BN * 32];

    const int tid = threadIdx.x;
    const int wave = tid >> 6, lane = tid & 63;
    const int col = lane & 15, quad = lane >> 4;
    const int wm = wave >> 1, wn = wave & 1;
    const int row0 = blockIdx.y << 7, col0 = blockIdx.x * BN;

    f32x4 acc[4][NJ] = {};

    const u16* asrc[2];
    u16* adst[2];
    #pragma unroll
    for (int is = 0; is < 2; ++is) {
        const int J = is * 256 + wave * 64 + lane;
        const int m = J >> 2;
        const int q = (J & 3) ^ ((m >> 1) & 3);
        asrc[is] = A + (size_t)(row0 + m) * K + q * 8;
        adst[is] = &As[(size_t)(is * 256 + wave * 64) * 8];
    }
    const u16* bsrc[BIS];
    u16* bdst[BIS];
    #pragma unroll
    for (int is = 0; is < BIS; ++is) {
        const int J = is * 256 + wave * 64 + lane;
        const int m = J >> 2;
        const int q = (J & 3) ^ ((m >> 1) & 3);
        bsrc[is] = BT + (size_t)(col0 + m) * K + q * 8;
        bdst[is] = &Bs[(size_t)(is * 256 + wave * 64) * 8];
    }

    for (int kk = 0; kk < K; kk += 32) {
        __syncthreads();
        #pragma unroll
        for (int is = 0; is < 2; ++is)
            __builtin_amdgcn_global_load_lds(
                (const __attribute__((address_space(1))) unsigned int*)(asrc[is] + kk),
                (__attribute__((address_space(3))) unsigned int*)adst[is], 16, 0, 0);
        #pragma unroll
        for (int is = 0; is < BIS; ++is)
            __builtin_amdgcn_global_load_lds(
                (const __attribute__((address_space(1))) unsigned int*)(bsrc[is] + kk),
                (__attribute__((address_space(3))) unsigned int*)bdst[is], 16, 0, 0);
        __syncthreads();

        short8 af[4], bf[NJ];
        #pragma unroll
        for (int i = 0; i < 4; ++i) {
            const int m = wm * 64 + i * 16 + col;
            af[i] = *(const short8*)&As[(m * 4 + (quad ^ ((m >> 1) & 3))) * 8];
        }
        #pragma unroll
        for (int j = 0; j < NJ; ++j) {
            const int n = wn * (BN / 2) + j * 16 + col;
            bf[j] = *(const short8*)&Bs[(n * 4 + (quad ^ ((n >> 1) & 3))) * 8];
        }
        #pragma unroll
        for (int i = 0; i < 4; ++i)
            #pragma unroll
            for (int j = 0; j < NJ; ++j)
                acc[i][j] = __builtin_amdgcn_mfma_f32_16x16x32_bf16(
                    af[i], bf[j], acc[i][j], 0, 0, 0);
    }

    #pragma unroll
    for (int j = 0; j < NJ; ++j) {
        const int gc = col0 + wn * (BN / 2) + j * 16 + col;
        const float bj = bias[gc];
        #pragma unroll
        for (int i = 0; i < 4; ++i) {
            const int gr = row0 + wm * 64 + i * 16 + quad * 4;
            #pragma unroll
            for (int r = 0; r < 4; ++r) {
                const float v = acc[i][j][r] + bj;
                if (STORE_BF16)
                    ((u16*)C)[(size_t)(gr + r) * N + gc] = f2b(v);
                else
                    ((float*)C)[(size_t)(gr + r) * N + gc] = v;
            }
        }
    }
}

// ---------------------------------------------------------------------------
// MFMA flash attention, 2-WAVE BLOCKS (barrier-group granularity):
// Evidence R1-R3: dur = per-phase serial chain x phases / (independent
// barrier groups per CU); wave count per CU pinned at 8 by the grid.
// R1: ILP/VALU cuts neutral. R2: unpaired = no refill, regress. R3: KVB=128
// at 66 KB LDS = 1 block/CU (usable residency LDS ~128 KB, not 160), regress.
// => split the 8 waves/CU into 4 blocks of 2 waves instead of 2 blocks of 4:
// 32-row q-tiles, pairs qtA + qtB = 63, grid 32x32 = 1024 blocks, uniform
// 33 process-calls/block. Each SIMD then carries 2 waves from DIFFERENT
// barrier groups -> one block's vmcnt(0)+s_barrier drain is always covered
// by the other; 4 staggered DMA pipelines per CU. LDS 29.7 KB -> 4 blocks/CU.
// Keeps: XOR-swizzled K stage via global_load_lds, K-DMA aged one phase,
// reg-staged V transpose, per-wave-private Ps strips, transposed-S
// in-register softmax, cvt_pk P->bf16, defer-max (T13), setprio (T5).
__global__ __launch_bounds__(128) void attn_kernel(
    const u16* __restrict__ qkv, u16* __restrict__ vals)
{
    __shared__ u16 Ks[2][KVB * 64];   // 2 x 8 KB, XOR-swizzled 16B chunks
    __shared__ u16 Vt[64 * PADV];     // 8.5 KB, transposed V
    __shared__ u16 Ps[QTB * PADP];    // 4.5 KB, per-wave 16-row strips

    const int tid = threadIdx.x;
    const int wave = tid >> 6, lane = tid & 63;
    const int col = lane & 15, quad = lane >> 4;
    const int qtA = blockIdx.x;          // 0..31
    const int qtB = 63 - qtA;            // 32..63
    const int bh = blockIdx.y;
    const int b = bh >> 4, h = bh & 15;
    const size_t base = (size_t)b * NS * QLD + (size_t)h * (3 * NHD);
    const int qloc = wave * 16 + col;    // this lane's query (tile-local, 0..31)

    // DMA decomposition: J = is*128 + tid; row m=J>>3, stored chunk position
    // c'=J&7 holds source chunk c = c' ^ (m&7).
    int Jrow[4], Jcol[4];
    #pragma unroll
    for (int is = 0; is < 4; ++is) {
        const int J = is * 128 + tid;
        Jrow[is] = J >> 3;
        Jcol[is] = ((J & 7) ^ (Jrow[is] & 7)) << 3;
    }

    auto stage_k = [&](int buf, int kt) {   // 64 rows, 4 DMA instrs
        #pragma unroll
        for (int is = 0; is < 4; ++is) {
            __builtin_amdgcn_global_load_lds(
                (const __attribute__((address_space(1))) unsigned int*)
                    (qkv + base + (size_t)(kt * KVB + Jrow[is]) * QLD + NHD + Jcol[is]),
                (__attribute__((address_space(3))) unsigned int*)
                    &Ks[buf][(size_t)(is * 128 + wave * 64) * 8], 16, 0, 0);
        }
    };
    auto stage_q = [&](int buf, int qt) {   // 32 rows, 2 DMA instrs
        #pragma unroll
        for (int is = 0; is < 2; ++is) {
            __builtin_amdgcn_global_load_lds(
                (const __attribute__((address_space(1))) unsigned int*)
                    (qkv + base + (size_t)(qt * QTB + Jrow[is]) * QLD + Jcol[is]),
                (__attribute__((address_space(3))) unsigned int*)
                    &Ks[buf][(size_t)(is * 128 + wave * 64) * 8], 16, 0, 0);
        }
    };
    // fragment read from swizzled Ks[buf]: row, d-half -> (row, half*32+quad*8..+7)
    auto read_frag = [&](int buf, int row, int half) -> short8 {
        const int blk = row * 8 + ((quad + (half << 2)) ^ (row & 7));
        return *(const short8*)&Ks[buf][blk << 3];
    };

    // V reg-staging lanes: vtx -> 4 d-values, vty -> 8 kv-rows
    const int vtx = tid & 15, vty = tid >> 4;
    const int vk0 = vty << 3, vd0 = vtx << 2;
    auto load_vregs = [&](int kt, ushort4* vr) {
        const u16* vsrc = qkv + base + (size_t)(kt * KVB + vk0) * QLD + 2 * NHD + vd0;
        #pragma unroll
        for (int j = 0; j < 8; ++j) vr[j] = *(const ushort4*)(vsrc + j * QLD);
    };
    auto write_vt = [&](const ushort4* vr) {
        *(ushort4*)&Vt[(vd0 + 0) * PADV + vk0]     = make_ushort4(vr[0].x, vr[1].x, vr[2].x, vr[3].x);
        *(ushort4*)&Vt[(vd0 + 0) * PADV + vk0 + 4] = make_ushort4(vr[4].x, vr[5].x, vr[6].x, vr[7].x);
        *(ushort4*)&Vt[(vd0 + 1) * PADV + vk0]     = make_ushort4(vr[0].y, vr[1].y, vr[2].y, vr[3].y);
        *(ushort4*)&Vt[(vd0 + 1) * PADV + vk0 + 4] = make_ushort4(vr[4].y, vr[5].y, vr[6].y, vr[7].y);
        *(ushort4*)&Vt[(vd0 + 2) * PADV + vk0]     = make_ushort4(vr[0].z, vr[1].z, vr[2].z, vr[3].z);
        *(ushort4*)&Vt[(vd0 + 2) * PADV + vk0 + 4] = make_ushort4(vr[4].z, vr[5].z, vr[6].z, vr[7].z);
        *(ushort4*)&Vt[(vd0 + 3) * PADV + vk0]     = make_ushort4(vr[0].w, vr[1].w, vr[2].w, vr[3].w);
        *(ushort4*)&Vt[(vd0 + 3) * PADV + vk0 + 4] = make_ushort4(vr[4].w, vr[5].w, vr[6].w, vr[7].w);
    };

    // ---- prologue: Q_A -> Ks[0], Q_B -> Ks[1] (lower quarters); hoist ----
    stage_q(0, qtA);
    stage_q(1, qtB);
    __syncthreads();
    short8 bqA0 = read_frag(0, qloc, 0), bqA1 = read_frag(0, qloc, 1);
    short8 bqB0 = read_frag(1, qloc, 0), bqB1 = read_frag(1, qloc, 1);
    __syncthreads();                     // Q reads done before K(0) overwrites

    f32x4 accA[4] = {}, accB[4] = {};
    float mA = -1e30f, lA = 0.f, mB = -1e30f, lB = 0.f;

    auto qk = [&](const short8& b0, const short8& b1,
                  short8 (&kb)[4][2], f32x4 (&s)[4]) {
        __builtin_amdgcn_s_setprio(1);
        #pragma unroll
        for (int kg = 0; kg < 4; ++kg) {
            s[kg] = __builtin_amdgcn_mfma_f32_16x16x32_bf16(kb[kg][0], b0, s[kg], 0, 0, 0);
            s[kg] = __builtin_amdgcn_mfma_f32_16x16x32_bf16(kb[kg][1], b1, s[kg], 0, 0, 0);
        }
        __builtin_amdgcn_s_setprio(0);
    };

    auto sm = [&](f32x4 (&s)[4], f32x4 (&acc)[4], float& m, float& l,
                  bool diag, int th) {
        #pragma unroll
        for (int kg = 0; kg < 4; ++kg)
            #pragma unroll
            for (int r = 0; r < 4; ++r) {
                float v = s[kg][r] * 0.125f;
                if (diag && (kg * 16 + quad * 4 + r > th)) v = -1e30f;
                s[kg][r] = v;
            }
        float mx = -1e30f;
        #pragma unroll
        for (int kg = 0; kg < 4; ++kg)
            mx = fmaxf(mx, fmaxf(fmaxf(s[kg][0], s[kg][1]), fmaxf(s[kg][2], s[kg][3])));
        mx = fmaxf(mx, __shfl_xor(mx, 16, 64));
        mx = fmaxf(mx, __shfl_xor(mx, 32, 64));
        // defer-max (T13): rescale only when some query's max grew past m+8.
        if (!__all(mx <= m + 8.f)) {
            const float mn = fmaxf(m, mx);
            const float alpha = __expf(m - mn);
            m = mn;
            l *= alpha;
            #pragma unroll
            for (int dg = 0; dg < 4; ++dg)
                #pragma unroll
                for (int r = 0; r < 4; ++r) acc[dg][r] *= alpha;
        }
        float psum = 0.f;
        #pragma unroll
        for (int kg = 0; kg < 4; ++kg) {
            float p0 = __expf(s[kg][0] - m);
            float p1 = __expf(s[kg][1] - m);
            float p2 = __expf(s[kg][2] - m);
            float p3 = __expf(s[kg][3] - m);
            psum += (p0 + p1) + (p2 + p3);
            uint2 w;
            w.x = cvtpk(p0, p1);
            w.y = cvtpk(p2, p3);
            *(uint2*)&Ps[qloc * PADP + kg * 16 + quad * 4] = w;
        }
        psum += __shfl_xor(psum, 16, 64);
        psum += __shfl_xor(psum, 32, 64);
        l += psum;
    };

    auto pv = [&](short8 (&vb)[4][2], f32x4 (&acc)[4]) {
        short8 pb0 = *(const short8*)&Ps[qloc * PADP + quad * 8];
        short8 pb1 = *(const short8*)&Ps[qloc * PADP + 32 + quad * 8];
        __builtin_amdgcn_s_setprio(1);
        #pragma unroll
        for (int dg = 0; dg < 4; ++dg) {
            acc[dg] = __builtin_amdgcn_mfma_f32_16x16x32_bf16(vb[dg][0], pb0, acc[dg], 0, 0, 0);
            acc[dg] = __builtin_amdgcn_mfma_f32_16x16x32_bf16(vb[dg][1], pb1, acc[dg], 0, 0, 0);
        }
        __builtin_amdgcn_s_setprio(0);
    };

    // ---- software pipeline ----
    // kv-tiles needed for 32-row tile qt: 0 .. qt>>1 (64-row kv tiles).
    const int qtAh = qtA >> 1, qtBh = qtB >> 1;   // A: 0..15, B: 16..31
    const int thA = qloc + ((qtA & 1) << 5);      // diag threshold (local kv idx)
    const int thB = qloc + ((qtB & 1) << 5);
    ushort4 vcur[8], vnxt[8];
    stage_k(0, 0);                       // K(0) -> Ks[0]
    load_vregs(0, vcur);

    for (int kt = 0; kt <= qtBh; ++kt) {
        const int cur = kt & 1, nxt = cur ^ 1;
        __syncthreads();                 // (A) drains K(kt) DMA; Vt reads done
        write_vt(vcur);
        __syncthreads();                 // (B) Vt visible
        if (kt < qtBh) {
            stage_k(nxt, kt + 1);        // in flight during compute
            load_vregs(kt + 1, vnxt);
        }

        // read K/V fragments once, reuse for both q-tiles
        short8 kb[4][2], vb[4][2];
        #pragma unroll
        for (int kg = 0; kg < 4; ++kg) {
            kb[kg][0] = read_frag(cur, kg * 16 + col, 0);
            kb[kg][1] = read_frag(cur, kg * 16 + col, 1);
        }
        #pragma unroll
        for (int dg = 0; dg < 4; ++dg) {
            const int n = dg * 16 + col;
            short4v lo0 = *(const short4v*)&Vt[n * PADV + quad * 8];
            short4v hi0 = *(const short4v*)&Vt[n * PADV + quad * 8 + 4];
            short4v lo1 = *(const short4v*)&Vt[n * PADV + 32 + quad * 8];
            short4v hi1 = *(const short4v*)&Vt[n * PADV + 32 + quad * 8 + 4];
            vb[dg][0] = __builtin_shufflevector(lo0, hi0, 0, 1, 2, 3, 4, 5, 6, 7);
            vb[dg][1] = __builtin_shufflevector(lo1, hi1, 0, 1, 2, 3, 4, 5, 6, 7);
        }

        {
            // kt <= qtBh; B diagonal only at kt == qtBh (then kt > qtAh,
            // so the A-branch below is inactive -- no double-diag phase).
            f32x4 s[4] = {};
            qk(bqB0, bqB1, kb, s);
            sm(s, accB, mB, lB, kt == qtBh, thB);
            pv(vb, accB);
        }
        if (kt <= qtAh) {
            f32x4 s[4] = {};
            qk(bqA0, bqA1, kb, s);
            sm(s, accA, mA, lA, kt == qtAh, thA);
            pv(vb, accA);
        }

        #pragma unroll
        for (int i = 0; i < 8; ++i) vcur[i] = vnxt[i];
    }

    // ---- epilogue: O^T rows d = dg*16 + quad*4 + r, query qloc ----
    {
        const float inv = 1.f / lA;
        const size_t rowoff = ((size_t)b * NS + qtA * QTB + qloc) * ND + h * NHD;
        #pragma unroll
        for (int dg = 0; dg < 4; ++dg) {
            uint2 o;
            o.x = cvtpk(accA[dg][0] * inv, accA[dg][1] * inv);
            o.y = cvtpk(accA[dg][2] * inv, accA[dg][3] * inv);
            *(uint2*)(vals + rowoff + dg * 16 + quad * 4) = o;
        }
    }
    {
        const float inv = 1.f / lB;
        const size_t rowoff = ((size_t)b * NS + qtB * QTB + qloc) * ND + h * NHD;
        #pragma unroll
        for (int dg = 0; dg < 4; ++dg) {
            uint2 o;
            o.x = cvtpk(accB[dg][0] * inv, accB[dg][1] * inv);
            o.y = cvtpk(accB[dg][2] * inv, accB[dg][3] * inv);
            *(uint2*)(vals + rowoff + dg * 16 + quad * 4) = o;
        }
    }
}

extern "C" void kernel_launch(void* const* d_in, const int* in_sizes, int n_in,
                              void* d_out, int out_size, void* d_ws, size_t ws_size,
                              hipStream_t stream)
{
    // inputs: x, mask(unused), W_qkv, b_qkv, W_o, b_o  -- all fp32
    const float* x    = (const float*)d_in[0];
    const float* Wqkv = (const float*)d_in[2];
    const float* bqkv = (const float*)d_in[3];
    const float* Wo   = (const float*)d_in[4];
    const float* bo   = (const float*)d_in[5];
    float* out = (float*)d_out;

    u16* x_bf   = (u16*)d_ws;                       //  4096*1024
    u16* WqkvT  = x_bf   + (size_t)4096 * 1024;     //  3072*1024  [N,K]
    u16* WoT    = WqkvT  + (size_t)3072 * 1024;     //  1024*1024  [N,K]
    u16* qkv    = WoT    + (size_t)1024 * 1024;     //  4096*3072
    u16* vals   = qkv    + (size_t)4096 * 3072;     //  4096*1024

    const int M = NB * NS;  // 4096

    convert_bf16<<<dim3(M * ND / (256 * 8)), dim3(256), 0, stream>>>(
        x, x_bf, M * ND);
    transpose_bf16<<<dim3(QLD / 64, ND / 64), dim3(256), 0, stream>>>(
        Wqkv, WqkvT, ND, QLD);
    transpose_bf16<<<dim3(ND / 64, ND / 64), dim3(256), 0, stream>>>(
        Wo, WoT, ND, ND);

    gemm_mfma<128, true><<<dim3(QLD / 128, M / 128), dim3(256), 0, stream>>>(
        x_bf, WqkvT, bqkv, qkv, M, QLD, ND);
    attn_kernel<<<dim3(32, NB * NH), dim3(128), 0, stream>>>(qkv, vals);
    gemm_mfma<64, false><<<dim3(ND / 64, M / 128), dim3(256), 0, stream>>>(
        vals, WoT, bo, out, M, ND, ND);
}

// Round 6
// 210.845 us; speedup vs baseline: 1.1541x; 1.0329x over previous
//
#include <hip/hip_runtime.h>

// Problem constants (B=2, S=2048, D=1024, H=16, HD=64). fp32 in / fp32 out.
#define NB 2
#define NS 2048
#define ND 1024
#define NH 16
#define NHD 64
#define QLD (3 * ND)   // qkv workspace row stride in elements = 3072
#define PADP 72        // Ps row stride (u16); 144 B = 16B-aligned rows
#define PADV 68        // Vt row stride (u16)

typedef unsigned short u16;
typedef __attribute__((ext_vector_type(8))) short short8;   // 8 x bf16 (4 VGPRs)
typedef __attribute__((ext_vector_type(4))) short short4v;  // 4 x bf16 (2 VGPRs)
typedef __attribute__((ext_vector_type(4))) float f32x4;

__device__ __forceinline__ u16 f2b(float f) {
    unsigned int x = __float_as_uint(f);
    return (u16)((x + 0x7fffu + ((x >> 16) & 1u)) >> 16);  // RNE
}

// v_cvt_pk_bf16_f32: low16 = bf16(lo), high16 = bf16(hi), RNE.
__device__ __forceinline__ unsigned int cvtpk(float lo, float hi) {
    unsigned int r;
    asm("v_cvt_pk_bf16_f32 %0, %1, %2" : "=v"(r) : "v"(lo), "v"(hi));
    return r;
}

// ---------------------------------------------------------------------------
// Fused prep: x fp32->bf16 cast + both weight transposes (W[K,N] fp32 ->
// WT[N,K] bf16). One launch instead of three: non-attn wall time is ~150 us
// across all rounds while kernel durs sum lower -- launch gaps are real.
__global__ __launch_bounds__(256) void prep(
    const float* __restrict__ x, u16* __restrict__ x_bf,
    const float* __restrict__ Wqkv, u16* __restrict__ WqkvT,
    const float* __restrict__ Wo, u16* __restrict__ WoT)
{
    __shared__ u16 Ts[64 * 72];
    const int bid = blockIdx.x;
    const int t = threadIdx.x;

    if (bid < 2048) {                    // convert x: 4096*1024 elems
        const int i = (bid * 256 + t) * 8;
        float4 a = *(const float4*)(x + i);
        float4 b = *(const float4*)(x + i + 4);
        *(ushort4*)(x_bf + i)     = make_ushort4(f2b(a.x), f2b(a.y), f2b(a.z), f2b(a.w));
        *(ushort4*)(x_bf + i + 4) = make_ushort4(f2b(b.x), f2b(b.y), f2b(b.z), f2b(b.w));
        return;
    }

    const float* W; u16* WT; int N, bx, by;
    if (bid < 2048 + 768) {              // W_qkv: K=1024, N=3072 -> 48x16 tiles
        const int r = bid - 2048;
        W = Wqkv; WT = WqkvT; N = QLD; bx = r % 48; by = r / 48;
    } else {                             // W_o: K=1024, N=1024 -> 16x16 tiles
        const int r = bid - 2816;
        W = Wo; WT = WoT; N = ND; bx = r & 15; by = r >> 4;
    }
    const int K = ND;
    const int k0 = by << 6, n0 = bx << 6;
    const int rr0 = t >> 4, c = (t & 15) << 2;
    #pragma unroll
    for (int rr = 0; rr < 64; rr += 16) {
        float4 v = *(const float4*)&W[(size_t)(k0 + rr0 + rr) * N + n0 + c];
        Ts[(c + 0) * 72 + rr0 + rr] = f2b(v.x);
        Ts[(c + 1) * 72 + rr0 + rr] = f2b(v.y);
        Ts[(c + 2) * 72 + rr0 + rr] = f2b(v.z);
        Ts[(c + 3) * 72 + rr0 + rr] = f2b(v.w);
    }
    __syncthreads();
    const int n = t >> 2, cc = (t & 3) << 4;
    uint4 a = *(const uint4*)&Ts[n * 72 + cc];
    uint4 b = *(const uint4*)&Ts[n * 72 + cc + 8];
    *(uint4*)&WT[(size_t)(n0 + n) * K + k0 + cc]     = a;
    *(uint4*)&WT[(size_t)(n0 + n) * K + k0 + cc + 8] = b;
}

// ---------------------------------------------------------------------------
// bf16 MFMA GEMM (m97 structure): C[M,N] = A[M,K] @ BT[N,K]^T + bias[N].
// 128xBN tile, 256 threads, BK=32, global_load_lds w=16, XOR swizzle,
// + bijective XCD-aware block swizzle (T1; both grids divisible by 8).
template <int BN, bool STORE_BF16>
__global__ __launch_bounds__(256) void gemm_mfma(
    const u16* __restrict__ A, const u16* __restrict__ BT,
    const float* __restrict__ bias,
    void* __restrict__ C, int M, int N, int K)
{
    constexpr int BIS = BN / 64;   // B staging iterations
    constexpr int NJ  = BN / 32;   // per-wave N fragments
    __shared__ u16 As[128 * 32];
    __shared__ u16 Bs[BN * 32];

    const int tid = threadIdx.x;
    const int wave = tid >> 6, lane = tid & 63;
    const int col = lane & 15, quad = lane >> 4;
    const int wm = wave >> 1, wn = wave & 1;

    // XCD swizzle: HW round-robins linear block id across 8 XCDs; remap so
    // each XCD owns a contiguous tile range (L2 locality on shared panels).
    const int nwgx = gridDim.x;
    const int wg = blockIdx.y * nwgx + blockIdx.x;
    const int cpx = (nwgx * gridDim.y) >> 3;
    const int swz = (wg & 7) * cpx + (wg >> 3);
    const int row0 = (swz / nwgx) << 7, col0 = (swz % nwgx) * BN;

    f32x4 acc[4][NJ] = {};

    const u16* asrc[2];
    u16* adst[2];
    #pragma unroll
    for (int is = 0; is < 2; ++is) {
        const int J = is * 256 + wave * 64 + lane;
        const int m = J >> 2;
        const int q = (J & 3) ^ ((m >> 1) & 3);
        asrc[is] = A + (size_t)(row0 + m) * K + q * 8;
        adst[is] = &As[(size_t)(is * 256 + wave * 64) * 8];
    }
    const u16* bsrc[BIS];
    u16* bdst[BIS];
    #pragma unroll
    for (int is = 0; is < BIS; ++is) {
        const int J = is * 256 + wave * 64 + lane;
        const int m = J >> 2;
        const int q = (J & 3) ^ ((m >> 1) & 3);
        bsrc[is] = BT + (size_t)(col0 + m) * K + q * 8;
        bdst[is] = &Bs[(size_t)(is * 256 + wave * 64) * 8];
    }

    for (int kk = 0; kk < K; kk += 32) {
        __syncthreads();
        #pragma unroll
        for (int is = 0; is < 2; ++is)
            __builtin_amdgcn_global_load_lds(
                (const __attribute__((address_space(1))) unsigned int*)(asrc[is] + kk),
                (__attribute__((address_space(3))) unsigned int*)adst[is], 16, 0, 0);
        #pragma unroll
        for (int is = 0; is < BIS; ++is)
            __builtin_amdgcn_global_load_lds(
                (const __attribute__((address_space(1))) unsigned int*)(bsrc[is] + kk),
                (__attribute__((address_space(3))) unsigned int*)bdst[is], 16, 0, 0);
        __syncthreads();

        short8 af[4], bf[NJ];
        #pragma unroll
        for (int i = 0; i < 4; ++i) {
            const int m = wm * 64 + i * 16 + col;
            af[i] = *(const short8*)&As[(m * 4 + (quad ^ ((m >> 1) & 3))) * 8];
        }
        #pragma unroll
        for (int j = 0; j < NJ; ++j) {
            const int n = wn * (BN / 2) + j * 16 + col;
            bf[j] = *(const short8*)&Bs[(n * 4 + (quad ^ ((n >> 1) & 3))) * 8];
        }
        #pragma unroll
        for (int i = 0; i < 4; ++i)
            #pragma unroll
            for (int j = 0; j < NJ; ++j)
                acc[i][j] = __builtin_amdgcn_mfma_f32_16x16x32_bf16(
                    af[i], bf[j], acc[i][j], 0, 0, 0);
    }

    #pragma unroll
    for (int j = 0; j < NJ; ++j) {
        const int gc = col0 + wn * (BN / 2) + j * 16 + col;
        const float bj = bias[gc];
        #pragma unroll
        for (int i = 0; i < 4; ++i) {
            const int gr = row0 + wm * 64 + i * 16 + quad * 4;
            #pragma unroll
            for (int r = 0; r < 4; ++r) {
                const float v = acc[i][j][r] + bj;
                if (STORE_BF16)
                    ((u16*)C)[(size_t)(gr + r) * N + gc] = f2b(v);
                else
                    ((float*)C)[(size_t)(gr + r) * N + gc] = v;
            }
        }
    }
}

// ---------------------------------------------------------------------------
// MFMA flash attention: causal pairing, ONE barrier per phase (salvaged from
// failed R5 without the tr16 risk). Vt double-buffered: write_vt for tile
// kt+1 moved to the END of phase kt (write-late, T14 -- its global loads age
// through the full compute phase), reads hit Vt[cur] written a phase ago.
// Barriers/block: 66 -> 34. Everything else identical to the measured-68.4
// R1 structure (LDS 43008 B -> 2 blocks/CU, swizzled K staging via
// global_load_lds, per-wave Ps strips, in-register transposed-S softmax,
// cvt_pk P->bf16, defer-max T13, setprio T5, K-DMA aged one full phase).
__global__ __launch_bounds__(256) void attn_kernel(
    const u16* __restrict__ qkv, u16* __restrict__ vals)
{
    __shared__ u16 Ks[2][64 * 64];    // 2 x 8 KB, XOR-swizzled 16B chunks
    __shared__ u16 Vt[2][64 * PADV];  // 2 x 8.5 KB, transposed V
    __shared__ u16 Ps[64 * PADP];     // 9 KB, per-wave 16-row strips

    const int tid = threadIdx.x;
    const int wave = tid >> 6, lane = tid & 63;
    const int col = lane & 15, quad = lane >> 4;
    const int qtA = blockIdx.x;          // 0..15
    const int qtB = 31 - qtA;            // 16..31
    const int bh = blockIdx.y;
    const int b = bh >> 4, h = bh & 15;
    const size_t base = (size_t)b * NS * QLD + (size_t)h * (3 * NHD);
    const int qloc = wave * 16 + col;    // this lane's query (tile-local)

    // DMA decomposition: J = is*256 + wave*64 + lane; row m=J>>3, stored
    // chunk position c'=J&7 holds source chunk c = c' ^ (m&7).
    int Jrow[2], Jcol[2];
    #pragma unroll
    for (int is = 0; is < 2; ++is) {
        const int J = is * 256 + wave * 64 + lane;
        Jrow[is] = J >> 3;
        Jcol[is] = ((J & 7) ^ (Jrow[is] & 7)) << 3;
    }

    auto stage_tile = [&](int buf, int srow, int coloff) {
        #pragma unroll
        for (int is = 0; is < 2; ++is) {
            __builtin_amdgcn_global_load_lds(
                (const __attribute__((address_space(1))) unsigned int*)
                    (qkv + base + (size_t)(srow + Jrow[is]) * QLD + coloff + Jcol[is]),
                (__attribute__((address_space(3))) unsigned int*)
                    &Ks[buf][(size_t)(is * 256 + wave * 64) * 8], 16, 0, 0);
        }
    };
    // fragment read from swizzled Ks[buf]: row, d-half -> (row, half*32+quad*8..+7)
    auto read_frag = [&](int buf, int row, int half) -> short8 {
        const int blk = row * 8 + ((quad + (half << 2)) ^ (row & 7));
        return *(const short8*)&Ks[buf][blk << 3];
    };

    // V reg-staging lanes
    const int vtx = tid & 15, vty = tid >> 4;
    const int vk0 = vty << 2, vd0 = vtx << 2;
    auto load_vregs = [&](int kt, ushort4* vr) {
        const u16* vsrc = qkv + base + (size_t)(kt * 64 + vk0) * QLD + 2 * NHD + vd0;
        vr[0] = *(const ushort4*)(vsrc);
        vr[1] = *(const ushort4*)(vsrc + QLD);
        vr[2] = *(const ushort4*)(vsrc + 2 * QLD);
        vr[3] = *(const ushort4*)(vsrc + 3 * QLD);
    };
    auto write_vt = [&](int buf, const ushort4* vr) {
        *(ushort4*)&Vt[buf][(vd0 + 0) * PADV + vk0] =
            make_ushort4(vr[0].x, vr[1].x, vr[2].x, vr[3].x);
        *(ushort4*)&Vt[buf][(vd0 + 1) * PADV + vk0] =
            make_ushort4(vr[0].y, vr[1].y, vr[2].y, vr[3].y);
        *(ushort4*)&Vt[buf][(vd0 + 2) * PADV + vk0] =
            make_ushort4(vr[0].z, vr[1].z, vr[2].z, vr[3].z);
        *(ushort4*)&Vt[buf][(vd0 + 3) * PADV + vk0] =
            make_ushort4(vr[0].w, vr[1].w, vr[2].w, vr[3].w);
    };

    // ---- prologue: stage Q_A -> Ks[0], Q_B -> Ks[1]; hoist B-fragments ----
    stage_tile(0, qtA * 64, 0);
    stage_tile(1, qtB * 64, 0);
    __syncthreads();
    short8 bqA0 = read_frag(0, qloc, 0), bqA1 = read_frag(0, qloc, 1);
    short8 bqB0 = read_frag(1, qloc, 0), bqB1 = read_frag(1, qloc, 1);
    __syncthreads();                     // Q reads done before K(0) overwrites

    f32x4 accA[4] = {}, accB[4] = {};
    float mA = -1e30f, lA = 0.f, mB = -1e30f, lB = 0.f;

    auto qk = [&](const short8& b0, const short8& b1,
                  short8 (&kb)[4][2], f32x4 (&s)[4]) {
        __builtin_amdgcn_s_setprio(1);
        #pragma unroll
        for (int kg = 0; kg < 4; ++kg) {
            s[kg] = __builtin_amdgcn_mfma_f32_16x16x32_bf16(kb[kg][0], b0, s[kg], 0, 0, 0);
            s[kg] = __builtin_amdgcn_mfma_f32_16x16x32_bf16(kb[kg][1], b1, s[kg], 0, 0, 0);
        }
        __builtin_amdgcn_s_setprio(0);
    };

    auto sm = [&](f32x4 (&s)[4], f32x4 (&acc)[4], float& m, float& l, bool diag) {
        #pragma unroll
        for (int kg = 0; kg < 4; ++kg)
            #pragma unroll
            for (int r = 0; r < 4; ++r) {
                float v = s[kg][r] * 0.125f;
                if (diag && (kg * 16 + quad * 4 + r > qloc)) v = -1e30f;
                s[kg][r] = v;
            }
        float mx = -1e30f;
        #pragma unroll
        for (int kg = 0; kg < 4; ++kg)
            mx = fmaxf(mx, fmaxf(fmaxf(s[kg][0], s[kg][1]), fmaxf(s[kg][2], s[kg][3])));
        mx = fmaxf(mx, __shfl_xor(mx, 16, 64));
        mx = fmaxf(mx, __shfl_xor(mx, 32, 64));
        if (!__all(mx <= m + 8.f)) {     // defer-max (T13)
            const float mn = fmaxf(m, mx);
            const float alpha = __expf(m - mn);
            m = mn;
            l *= alpha;
            #pragma unroll
            for (int dg = 0; dg < 4; ++dg)
                #pragma unroll
                for (int r = 0; r < 4; ++r) acc[dg][r] *= alpha;
        }
        float psum = 0.f;
        #pragma unroll
        for (int kg = 0; kg < 4; ++kg) {
            float p0 = __expf(s[kg][0] - m);
            float p1 = __expf(s[kg][1] - m);
            float p2 = __expf(s[kg][2] - m);
            float p3 = __expf(s[kg][3] - m);
            psum += (p0 + p1) + (p2 + p3);
            uint2 w;
            w.x = cvtpk(p0, p1);
            w.y = cvtpk(p2, p3);
            *(uint2*)&Ps[qloc * PADP + kg * 16 + quad * 4] = w;
        }
        psum += __shfl_xor(psum, 16, 64);
        psum += __shfl_xor(psum, 32, 64);
        l += psum;
    };

    auto pv = [&](short8 (&vb)[4][2], f32x4 (&acc)[4]) {
        short8 pb0 = *(const short8*)&Ps[qloc * PADP + quad * 8];
        short8 pb1 = *(const short8*)&Ps[qloc * PADP + 32 + quad * 8];
        __builtin_amdgcn_s_setprio(1);
        #pragma unroll
        for (int dg = 0; dg < 4; ++dg) {
            acc[dg] = __builtin_amdgcn_mfma_f32_16x16x32_bf16(vb[dg][0], pb0, acc[dg], 0, 0, 0);
            acc[dg] = __builtin_amdgcn_mfma_f32_16x16x32_bf16(vb[dg][1], pb1, acc[dg], 0, 0, 0);
        }
        __builtin_amdgcn_s_setprio(0);
    };

    // ---- software pipeline: ONE barrier per phase ----
    // Vt[cur] is written at the END of phase kt-1 (or prologue for kt=0);
    // the single barrier at top of phase kt makes it visible, drains the
    // K(kt) DMA (issued top of phase kt-1, aged one full compute phase),
    // and orders prev-phase Vt[nxt] readers before this phase's writers.
    ushort4 vr[4];
    stage_tile(0, 0, NHD);               // K(0) -> Ks[0]
    load_vregs(0, vr);
    write_vt(0, vr);                     // Vt[0]; no reader before first barrier

    for (int kt = 0; kt <= qtB; ++kt) {
        const int cur = kt & 1, nxt = cur ^ 1;
        __syncthreads();
        if (kt < qtB) {
            stage_tile(nxt, (kt + 1) * 64, NHD);  // in flight during compute
            load_vregs(kt + 1, vr);               // consumed by write_vt below
        }

        // read K/V fragments once, reuse for both q-tiles
        short8 kb[4][2], vb[4][2];
        #pragma unroll
        for (int kg = 0; kg < 4; ++kg) {
            kb[kg][0] = read_frag(cur, kg * 16 + col, 0);
            kb[kg][1] = read_frag(cur, kg * 16 + col, 1);
        }
        #pragma unroll
        for (int dg = 0; dg < 4; ++dg) {
            const int n = dg * 16 + col;
            short4v lo0 = *(const short4v*)&Vt[cur][n * PADV + quad * 8];
            short4v hi0 = *(const short4v*)&Vt[cur][n * PADV + quad * 8 + 4];
            short4v lo1 = *(const short4v*)&Vt[cur][n * PADV + 32 + quad * 8];
            short4v hi1 = *(const short4v*)&Vt[cur][n * PADV + 32 + quad * 8 + 4];
            vb[dg][0] = __builtin_shufflevector(lo0, hi0, 0, 1, 2, 3, 4, 5, 6, 7);
            vb[dg][1] = __builtin_shufflevector(lo1, hi1, 0, 1, 2, 3, 4, 5, 6, 7);
        }

        {
            f32x4 s[4] = {};
            qk(bqB0, bqB1, kb, s);
            sm(s, accB, mB, lB, kt == qtB);
            pv(vb, accB);
        }
        if (kt <= qtA) {
            f32x4 s[4] = {};
            qk(bqA0, bqA1, kb, s);
            sm(s, accA, mA, lA, kt == qtA);
            pv(vb, accA);
        }

        if (kt < qtB) write_vt(nxt, vr); // write-late: loads aged thru compute
    }

    // ---- epilogue: O^T rows d = dg*16 + quad*4 + r, query qloc ----
    {
        const float inv = 1.f / lA;
        const size_t rowoff = ((size_t)b * NS + qtA * 64 + qloc) * ND + h * NHD;
        #pragma unroll
        for (int dg = 0; dg < 4; ++dg) {
            uint2 o;
            o.x = cvtpk(accA[dg][0] * inv, accA[dg][1] * inv);
            o.y = cvtpk(accA[dg][2] * inv, accA[dg][3] * inv);
            *(uint2*)(vals + rowoff + dg * 16 + quad * 4) = o;
        }
    }
    {
        const float inv = 1.f / lB;
        const size_t rowoff = ((size_t)b * NS + qtB * 64 + qloc) * ND + h * NHD;
        #pragma unroll
        for (int dg = 0; dg < 4; ++dg) {
            uint2 o;
            o.x = cvtpk(accB[dg][0] * inv, accB[dg][1] * inv);
            o.y = cvtpk(accB[dg][2] * inv, accB[dg][3] * inv);
            *(uint2*)(vals + rowoff + dg * 16 + quad * 4) = o;
        }
    }
}

extern "C" void kernel_launch(void* const* d_in, const int* in_sizes, int n_in,
                              void* d_out, int out_size, void* d_ws, size_t ws_size,
                              hipStream_t stream)
{
    // inputs: x, mask(unused), W_qkv, b_qkv, W_o, b_o  -- all fp32
    const float* x    = (const float*)d_in[0];
    const float* Wqkv = (const float*)d_in[2];
    const float* bqkv = (const float*)d_in[3];
    const float* Wo   = (const float*)d_in[4];
    const float* bo   = (const float*)d_in[5];
    float* out = (float*)d_out;

    u16* x_bf   = (u16*)d_ws;                       //  4096*1024
    u16* WqkvT  = x_bf   + (size_t)4096 * 1024;     //  3072*1024  [N,K]
    u16* WoT    = WqkvT  + (size_t)3072 * 1024;     //  1024*1024  [N,K]
    u16* qkv    = WoT    + (size_t)1024 * 1024;     //  4096*3072
    u16* vals   = qkv    + (size_t)4096 * 3072;     //  4096*1024

    const int M = NB * NS;  // 4096

    prep<<<dim3(2048 + 768 + 256), dim3(256), 0, stream>>>(
        x, x_bf, Wqkv, WqkvT, Wo, WoT);

    gemm_mfma<128, true><<<dim3(QLD / 128, M / 128), dim3(256), 0, stream>>>(
        x_bf, WqkvT, bqkv, qkv, M, QLD, ND);
    attn_kernel<<<dim3(16, NB * NH), dim3(256), 0, stream>>>(qkv, vals);
    gemm_mfma<64, false><<<dim3(ND / 64, M / 128), dim3(256), 0, stream>>>(
        vals, WoT, bo, out, M, ND, ND);
}